// Round 10
// baseline (427.684 us; speedup 1.0000x reference)
//
#include <hip/hip_runtime.h>
#include <cstdint>
#include <cstddef>

#define DMf 512
#define DM4 128
#define DIi 1024
#define DSs 16
#define DTRr 32
#define NLl 3
#define SDd 17
#define ADd 7
#define Bb 2
#define Ll 1024
#define NTOK (Bb*Ll)
#define CL 16
#define NCH 64

typedef __bf16 bf16x8 __attribute__((ext_vector_type(8)));
typedef float f32x4 __attribute__((ext_vector_type(4)));

__device__ inline unsigned short f2bf(float f){
  unsigned int u = __float_as_uint(f);
  unsigned int r = (u + 0x7FFFu + ((u>>16)&1u)) >> 16;
  return (unsigned short)r;
}
__device__ inline float silu_f(float v){ return v / (1.0f + __expf(-v)); }

// ---------------- cast fp32 -> bf16 (3 arrays in one launch) ----------------
__global__ __launch_bounds__(256) void cast3_k(
    const float* __restrict__ a, unsigned short* __restrict__ da, int na,
    const float* __restrict__ b, unsigned short* __restrict__ db, int nb,
    const float* __restrict__ c, unsigned short* __restrict__ dc, int nc){
  int i = blockIdx.x*256 + threadIdx.x;
  if (i < na) { da[i] = f2bf(a[i]); return; }
  int j = i - na;
  if (j < nb) { db[j] = f2bf(b[j]); return; }
  int k = j - nb;
  if (k < nc) dc[k] = f2bf(c[k]);
}

// ---------------- embedding ----------------
__global__ __launch_bounds__(128) void embed_k(
    const float* __restrict__ st, const float* __restrict__ ac,
    const float* __restrict__ rtg, const float* __restrict__ ctg,
    const int* __restrict__ ts,
    const float* __restrict__ Ws, const float* __restrict__ bs,
    const float* __restrict__ Wa, const float* __restrict__ ba,
    const float* __restrict__ Wr, const float* __restrict__ br,
    const float* __restrict__ Wc, const float* __restrict__ bc,
    const float* __restrict__ Et, float* __restrict__ x)
{
  int tok = blockIdx.x; int j = threadIdx.x;
  int l = tok & (Ll-1);
  int t = ts[tok];
  float te = Et[(size_t)t*DM4 + j];
  float re = rtg[tok]*Wr[j] + br[j] + te;
  float ce = ctg[tok]*Wc[j] + bc[j] + te;
  float se = bs[j] + te;
  #pragma unroll
  for (int k=0;k<SDd;++k) se += st[(size_t)tok*SDd+k]*Ws[j*SDd+k];
  float ae = 0.0f;
  if (l > 0) {
    int tp = ts[tok-1];
    ae = ba[j] + Et[(size_t)tp*DM4 + j];
    #pragma unroll
    for (int k=0;k<ADd;++k) ae += ac[(size_t)(tok-1)*ADd+k]*Wa[j*ADd+k];
  }
  float* xt = x + (size_t)tok*DMf;
  xt[0*DM4+j]=re; xt[1*DM4+j]=ce; xt[2*DM4+j]=se; xt[3*DM4+j]=ae;
}

// ---------------- layernorm -> bf16 (wave per token) ----------------
__global__ __launch_bounds__(256) void ln_k(const float* __restrict__ x,
    const float* __restrict__ g, const float* __restrict__ bta,
    unsigned short* __restrict__ xn)
{
  int wave = threadIdx.x >> 6, lane = threadIdx.x & 63;
  int tok = blockIdx.x*4 + wave;
  const float* xr = x + (size_t)tok*DMf;
  float v[8];
  float4 a = *(const float4*)&xr[lane*8];
  float4 b = *(const float4*)&xr[lane*8+4];
  v[0]=a.x; v[1]=a.y; v[2]=a.z; v[3]=a.w; v[4]=b.x; v[5]=b.y; v[6]=b.z; v[7]=b.w;
  float s = 0.f;
  #pragma unroll
  for (int j=0;j<8;++j) s += v[j];
  #pragma unroll
  for (int m=32;m>=1;m>>=1) s += __shfl_xor(s, m, 64);
  float mu = s * (1.0f/DMf);
  float vs = 0.f;
  #pragma unroll
  for (int j=0;j<8;++j){ float d = v[j]-mu; vs += d*d; }
  #pragma unroll
  for (int m=32;m>=1;m>>=1) vs += __shfl_xor(vs, m, 64);
  float rstd = rsqrtf(vs*(1.0f/DMf) + 1e-5f);
  unsigned int o[8];
  #pragma unroll
  for (int j=0;j<8;++j){
    int c = lane*8+j;
    o[j] = f2bf((v[j]-mu)*rstd*g[c] + bta[c]);
  }
  uint4 w;
  w.x = o[0] | (o[1]<<16); w.y = o[2] | (o[3]<<16);
  w.z = o[4] | (o[5]<<16); w.w = o[6] | (o[7]<<16);
  *(uint4*)&xn[(size_t)tok*DMf + lane*8] = w;
}

// ---------------- bf16 MFMA GEMM, C[M,N] = A[M,K] @ B[N,K]^T ----------------
// 128x128 tile, BK=32, 4 waves (2x2 of 64x64), global_load_lds width 16.
// Single-buffer + __syncthreads: measured-best (385us run); explicit 2-phase
// pipeline with sched_barrier(0) REGRESSED (r8: 421us) - compiler schedules better.
template<int ACCUM>
__global__ __launch_bounds__(256) void gemm_bt_k(const unsigned short* __restrict__ A,
    const unsigned short* __restrict__ Bm, float* __restrict__ C, int M, int N, int K)
{
  __shared__ unsigned short As[128*32];
  __shared__ unsigned short Bs[128*32];
  int tid = threadIdx.x;
  int bm = blockIdx.x, bn = blockIdx.y;
  size_t row0 = (size_t)bm*128, col0 = (size_t)bn*128;
  int wave = tid>>6, lane = tid&63;
  int wr = wave>>1, wc = wave&1;
  f32x4 acc[4][4];
  f32x4 z4 = {0.f,0.f,0.f,0.f};
  #pragma unroll
  for (int m=0;m<4;++m)
    #pragma unroll
    for (int n=0;n<4;++n) acc[m][n] = z4;
  int lrow = lane&15, lko = (lane>>4)*8;
  for (int k0=0; k0<K; k0+=32){
    #pragma unroll
    for (int r=0;r<2;++r){
      int flat = r*256 + tid;
      int arow = flat>>2, ak = (flat&3)*8;
      const unsigned short* ga = A + (row0+arow)*K + k0 + ak;
      const unsigned short* gb = Bm + (col0+arow)*K + k0 + ak;
      __builtin_amdgcn_global_load_lds((const __attribute__((address_space(1))) void*)ga,
          (__attribute__((address_space(3))) void*)(&As[flat*8]), 16, 0, 0);
      __builtin_amdgcn_global_load_lds((const __attribute__((address_space(1))) void*)gb,
          (__attribute__((address_space(3))) void*)(&Bs[flat*8]), 16, 0, 0);
    }
    __syncthreads();
    bf16x8 af[4], bfv[4];
    #pragma unroll
    for (int m=0;m<4;++m) af[m] = *(const bf16x8*)&As[(wr*64+m*16+lrow)*32 + lko];
    #pragma unroll
    for (int n=0;n<4;++n) bfv[n] = *(const bf16x8*)&Bs[(wc*64+n*16+lrow)*32 + lko];
    #pragma unroll
    for (int m=0;m<4;++m)
      #pragma unroll
      for (int n=0;n<4;++n)
        acc[m][n] = __builtin_amdgcn_mfma_f32_16x16x32_bf16(af[m], bfv[n], acc[m][n], 0, 0, 0);
    __syncthreads();
  }
  int lcol = lane&15, lr4 = (lane>>4)*4;
  #pragma unroll
  for (int m=0;m<4;++m)
    #pragma unroll
    for (int n=0;n<4;++n){
      size_t row = row0 + wr*64 + m*16 + lr4;
      size_t col = col0 + wc*64 + n*16 + lcol;
      #pragma unroll
      for (int j=0;j<4;++j){
        float vv = acc[m][n][j];
        float* p = &C[(row+j)*N + col];
        if (ACCUM) *p += vv; else *p = vv;
      }
    }
}

// ------- 64x64-tile bf16 MFMA GEMM (accumulating): C[M,N] += A[M,K] @ B[N,K]^T -------
__global__ __launch_bounds__(256) void gemm_bt64_k(const unsigned short* __restrict__ A,
    const unsigned short* __restrict__ Bm, float* __restrict__ C, int M, int N, int K)
{
  __shared__ unsigned short As[64*32];
  __shared__ unsigned short Bs[64*32];
  int tid = threadIdx.x;
  size_t row0 = (size_t)blockIdx.x*64, col0 = (size_t)blockIdx.y*64;
  int wave = tid>>6, lane = tid&63;
  int wr = wave>>1, wc = wave&1;
  f32x4 acc[2][2];
  f32x4 z4 = {0.f,0.f,0.f,0.f};
  acc[0][0]=z4; acc[0][1]=z4; acc[1][0]=z4; acc[1][1]=z4;
  int lrow = lane&15, lko = (lane>>4)*8;
  int srow = tid>>2, sk = (tid&3)*8;
  for (int k0=0; k0<K; k0+=32){
    const unsigned short* ga = A + (row0+srow)*K + k0 + sk;
    const unsigned short* gb = Bm + (col0+srow)*K + k0 + sk;
    __builtin_amdgcn_global_load_lds((const __attribute__((address_space(1))) void*)ga,
        (__attribute__((address_space(3))) void*)(&As[tid*8]), 16, 0, 0);
    __builtin_amdgcn_global_load_lds((const __attribute__((address_space(1))) void*)gb,
        (__attribute__((address_space(3))) void*)(&Bs[tid*8]), 16, 0, 0);
    __syncthreads();
    bf16x8 af[2], bfv[2];
    #pragma unroll
    for (int m=0;m<2;++m) af[m] = *(const bf16x8*)&As[(wr*32+m*16+lrow)*32 + lko];
    #pragma unroll
    for (int n=0;n<2;++n) bfv[n] = *(const bf16x8*)&Bs[(wc*32+n*16+lrow)*32 + lko];
    #pragma unroll
    for (int m=0;m<2;++m)
      #pragma unroll
      for (int n=0;n<2;++n)
        acc[m][n] = __builtin_amdgcn_mfma_f32_16x16x32_bf16(af[m], bfv[n], acc[m][n], 0, 0, 0);
    __syncthreads();
  }
  int lcol = lane&15, lr4 = (lane>>4)*4;
  #pragma unroll
  for (int m=0;m<2;++m)
    #pragma unroll
    for (int n=0;n<2;++n){
      size_t row = row0 + wr*32 + m*16 + lr4;
      size_t col = col0 + wc*32 + n*16 + lcol;
      #pragma unroll
      for (int j=0;j<4;++j)
        C[(row+j)*N + col] += acc[m][n][j];
    }
}

// ---------------- causal conv (width 4) + silu; fp32 + bf16 outputs ----------------
__global__ __launch_bounds__(256) void conv_k(const float* __restrict__ xz,
    const float* __restrict__ cw, const float* __restrict__ cb,
    float* __restrict__ xc, unsigned short* __restrict__ xcbf)
{
  int idx = blockIdx.x*256 + threadIdx.x;     // tok*DI + d
  int d = idx & (DIi-1); int tok = idx >> 10; int l = tok & (Ll-1);
  float acc = cb[d];
  #pragma unroll
  for (int k=0;k<4;++k){
    int ll = l + k - 3;
    if (ll >= 0) acc += xz[(size_t)(tok + k - 3)*(2*DIi) + d] * cw[d*4+k];
  }
  float v = silu_f(acc);
  xc[idx] = v;
  xcbf[idx] = f2bf(v);
}

// ---------------- xproj via MFMA: xdbl[2048,64] = xcbf @ xw^T, 64x64 tiles --------
__global__ __launch_bounds__(256) void xproj_mfma_k(const unsigned short* __restrict__ A,
    const unsigned short* __restrict__ Bw, float* __restrict__ xdbl)
{
  __shared__ unsigned short As[64*32];
  __shared__ unsigned short Bs[64*32];
  int tid = threadIdx.x;
  size_t row0 = (size_t)blockIdx.x*64;
  int wave = tid>>6, lane = tid&63;
  int wr = wave>>1, wc = wave&1;
  f32x4 acc[2][2];
  f32x4 z4 = {0.f,0.f,0.f,0.f};
  acc[0][0]=z4; acc[0][1]=z4; acc[1][0]=z4; acc[1][1]=z4;
  int lrow = lane&15, lko = (lane>>4)*8;
  int srow = tid>>2, sk = (tid&3)*8;
  for (int k0=0; k0<DIi; k0+=32){
    const unsigned short* ga = A + (row0+srow)*DIi + k0 + sk;
    const unsigned short* gb = Bw + (size_t)srow*DIi + k0 + sk;
    __builtin_amdgcn_global_load_lds((const __attribute__((address_space(1))) void*)ga,
        (__attribute__((address_space(3))) void*)(&As[tid*8]), 16, 0, 0);
    __builtin_amdgcn_global_load_lds((const __attribute__((address_space(1))) void*)gb,
        (__attribute__((address_space(3))) void*)(&Bs[tid*8]), 16, 0, 0);
    __syncthreads();
    bf16x8 af[2], bfv[2];
    #pragma unroll
    for (int m=0;m<2;++m) af[m] = *(const bf16x8*)&As[(wr*32+m*16+lrow)*32 + lko];
    #pragma unroll
    for (int n=0;n<2;++n) bfv[n] = *(const bf16x8*)&Bs[(wc*32+n*16+lrow)*32 + lko];
    #pragma unroll
    for (int m=0;m<2;++m)
      #pragma unroll
      for (int n=0;n<2;++n)
        acc[m][n] = __builtin_amdgcn_mfma_f32_16x16x32_bf16(af[m], bfv[n], acc[m][n], 0, 0, 0);
    __syncthreads();
  }
  int lcol = lane&15, lr4 = (lane>>4)*4;
  #pragma unroll
  for (int m=0;m<2;++m)
    #pragma unroll
    for (int n=0;n<2;++n){
      size_t row = row0 + wr*32 + m*16 + lr4;
      int col = wc*32 + n*16 + lcol;
      #pragma unroll
      for (int j=0;j<4;++j)
        xdbl[(row+j)*64 + col] = acc[m][n][j];
    }
}

// ---- scan pass 1 (dtproj folded in): per-chunk E (h from 0) and P (prod dA) ----
__global__ __launch_bounds__(256) void scan1_k(const float* __restrict__ xc,
    const float* __restrict__ xdbl, const float* __restrict__ dw,
    const float* __restrict__ dbias, const float* __restrict__ Alog,
    float* __restrict__ Ebuf, float* __restrict__ Pbuf)
{
  int bid = blockIdx.x;
  int dblk = bid & 3; int tmp = bid >> 2; int c = tmp & (NCH-1); int b = tmp >> 6;
  int d = dblk*256 + threadIdx.x;
  float w[32];
  #pragma unroll
  for (int q=0;q<8;++q) *(f32x4*)&w[q*4] = *(const f32x4*)&dw[(size_t)d*32 + q*4];
  float bias = dbias[d];
  float A[16], h[16], P[16];
  #pragma unroll
  for (int s=0;s<16;++s){ A[s] = -__expf(Alog[d*16+s]); h[s]=0.f; P[s]=1.f; }
  int l0 = c*CL;
  for (int l=l0; l<l0+CL; ++l){
    size_t tok = (size_t)b*Ll + l;
    const float* xrow = &xdbl[tok*64];
    float acc = bias;
    #pragma unroll
    for (int r=0;r<32;r+=4){
      f32x4 xv = *(const f32x4*)&xrow[r];
      acc += w[r]*xv[0] + w[r+1]*xv[1] + w[r+2]*xv[2] + w[r+3]*xv[3];
    }
    float dtv = (acc > 15.0f) ? acc : log1pf(__expf(acc));
    float u = xc[tok*DIi + d];
    float dtu = dtv*u;
    #pragma unroll
    for (int s=0;s<16;++s){
      float dA = __expf(dtv*A[s]);
      h[s] = h[s]*dA + dtu*xrow[32+s];
      P[s] *= dA;
    }
  }
  size_t base = (((size_t)b*DIi + d)*NCH + c)*16;
  #pragma unroll
  for (int s=0;s<16;++s){ Ebuf[base+s]=h[s]; Pbuf[base+s]=P[s]; }
}

// ---------------- combine chunk states ----------------
__global__ __launch_bounds__(256) void scanmid_k(const float* __restrict__ E,
    const float* __restrict__ P, float* __restrict__ H0)
{
  int gid = blockIdx.x*256 + threadIdx.x;   // (b*DI+d)*16 + s
  int s = gid & 15; size_t bd = (size_t)(gid >> 4);
  float H = 0.f;
  for (int c=0;c<NCH;++c){
    size_t idx = (bd*NCH + c)*16 + s;
    H0[idx] = H;
    H = P[idx]*H + E[idx];
  }
}

// ---- scan pass 2 (dtproj folded in): full y, gated, -> bf16 ----
__global__ __launch_bounds__(256) void scan2_k(const float* __restrict__ xc,
    const float* __restrict__ xdbl, const float* __restrict__ dw,
    const float* __restrict__ dbias, const float* __restrict__ Alog,
    const float* __restrict__ Dv, const float* __restrict__ xz,
    const float* __restrict__ H0, unsigned short* __restrict__ ybf)
{
  int bid = blockIdx.x;
  int dblk = bid & 3; int tmp = bid >> 2; int c = tmp & (NCH-1); int b = tmp >> 6;
  int d = dblk*256 + threadIdx.x;
  float w[32];
  #pragma unroll
  for (int q=0;q<8;++q) *(f32x4*)&w[q*4] = *(const f32x4*)&dw[(size_t)d*32 + q*4];
  float bias = dbias[d];
  size_t base = (((size_t)b*DIi + d)*NCH + c)*16;
  float A[16], h[16];
  #pragma unroll
  for (int s=0;s<16;++s){ A[s] = -__expf(Alog[d*16+s]); h[s] = H0[base+s]; }
  float Dd = Dv[d];
  int l0 = c*CL;
  for (int l=l0; l<l0+CL; ++l){
    size_t tok = (size_t)b*Ll + l;
    const float* xrow = &xdbl[tok*64];
    float acc = bias;
    #pragma unroll
    for (int r=0;r<32;r+=4){
      f32x4 xv = *(const f32x4*)&xrow[r];
      acc += w[r]*xv[0] + w[r+1]*xv[1] + w[r+2]*xv[2] + w[r+3]*xv[3];
    }
    float dtv = (acc > 15.0f) ? acc : log1pf(__expf(acc));
    float u = xc[tok*DIi + d];
    float dtu = dtv*u;
    float y = 0.f;
    #pragma unroll
    for (int s=0;s<16;++s){
      float dA = __expf(dtv*A[s]);
      h[s] = h[s]*dA + dtu*xrow[32+s];
      y += h[s]*xrow[48+s];
    }
    float zv = xz[tok*(2*DIi) + DIi + d];
    ybf[tok*DIi + d] = f2bf((y + Dd*u) * silu_f(zv));
  }
}

// ---------------- final LN + prediction heads ----------------
__global__ __launch_bounds__(256) void head_k(const float* __restrict__ x,
    const float* __restrict__ g, const float* __restrict__ bta,
    const float* __restrict__ Wps, const float* __restrict__ bps,
    const float* __restrict__ Wpa, const float* __restrict__ bpa,
    float* __restrict__ out)
{
  __shared__ float lds[4][256];
  int wave = threadIdx.x >> 6, lane = threadIdx.x & 63;
  int tok = blockIdx.x*4 + wave;
  const float* xr = x + (size_t)tok*DMf;
  float v[8];
  float4 a = *(const float4*)&xr[lane*8];
  float4 b = *(const float4*)&xr[lane*8+4];
  v[0]=a.x; v[1]=a.y; v[2]=a.z; v[3]=a.w; v[4]=b.x; v[5]=b.y; v[6]=b.z; v[7]=b.w;
  float s = 0.f;
  #pragma unroll
  for (int j=0;j<8;++j) s += v[j];
  #pragma unroll
  for (int m=32;m>=1;m>>=1) s += __shfl_xor(s, m, 64);
  float mu = s * (1.0f/DMf);
  float vs = 0.f;
  #pragma unroll
  for (int j=0;j<8;++j){ float d = v[j]-mu; vs += d*d; }
  #pragma unroll
  for (int m=32;m>=1;m>>=1) vs += __shfl_xor(vs, m, 64);
  float rstd = rsqrtf(vs*(1.0f/DMf) + 1e-5f);
  if (lane >= 32){
    #pragma unroll
    for (int j=0;j<8;++j){
      int cdx = lane*8+j;
      lds[wave][cdx-256] = (v[j]-mu)*rstd*g[cdx] + bta[cdx];
    }
  }
  __syncthreads();
  if (lane < SDd){
    float acc = bps[lane];
    const float* w = &Wps[lane*DM4];
    #pragma unroll 8
    for (int k=0;k<DM4;++k) acc += lds[wave][128+k]*w[k];   // slot 3 (ae)
    out[(size_t)tok*SDd + lane] = acc;
  } else if (lane < SDd+ADd){
    int o = lane - SDd;
    float acc = bpa[o];
    const float* w = &Wpa[o*DM4];
    #pragma unroll 8
    for (int k=0;k<DM4;++k) acc += lds[wave][k]*w[k];       // slot 2 (se)
    out[(size_t)NTOK*SDd + (size_t)tok*ADd + o] = acc;
  }
}

extern "C" void kernel_launch(void* const* d_in, const int* in_sizes, int n_in,
                              void* d_out, int out_size, void* d_ws, size_t ws_size,
                              hipStream_t stream)
{
  (void)in_sizes; (void)n_in; (void)out_size;
  const float* states   = (const float*)d_in[0];
  const float* actions  = (const float*)d_in[1];
  const float* rtg      = (const float*)d_in[2];
  const float* ctg      = (const float*)d_in[3];
  const int*   ts       = (const int*)d_in[4];
  const float* W_s      = (const float*)d_in[5];
  const float* b_s      = (const float*)d_in[6];
  const float* W_a      = (const float*)d_in[7];
  const float* b_a      = (const float*)d_in[8];
  const float* W_r      = (const float*)d_in[9];
  const float* b_r      = (const float*)d_in[10];
  const float* W_c      = (const float*)d_in[11];
  const float* b_c      = (const float*)d_in[12];
  const float* E_t      = (const float*)d_in[13];
  const float* ln_g     = (const float*)d_in[14];
  const float* ln_b     = (const float*)d_in[15];
  const float* in_w     = (const float*)d_in[16];
  const float* conv_w   = (const float*)d_in[17];
  const float* conv_b   = (const float*)d_in[18];
  const float* xproj_w  = (const float*)d_in[19];
  const float* dtproj_w = (const float*)d_in[20];
  const float* dtproj_b = (const float*)d_in[21];
  const float* A_log    = (const float*)d_in[22];
  const float* D_ssm    = (const float*)d_in[23];
  const float* out_w    = (const float*)d_in[24];
  const float* fn_g     = (const float*)d_in[25];
  const float* fn_b     = (const float*)d_in[26];
  const float* W_ps     = (const float*)d_in[27];
  const float* b_ps     = (const float*)d_in[28];
  const float* W_pa     = (const float*)d_in[29];
  const float* b_pa     = (const float*)d_in[30];

  char* ws = (char*)d_ws;
  constexpr size_t S_X    = (size_t)NTOK*DMf*4;       // 4 MB
  constexpr size_t S_XN   = (size_t)NTOK*DMf*2;       // 2 MB
  constexpr size_t S_XZ   = (size_t)NTOK*2*DIi*4;     // 16 MB
  constexpr size_t S_XC   = (size_t)NTOK*DIi*4;       // 8 MB
  constexpr size_t S_XCB  = (size_t)NTOK*DIi*2;       // 4 MB (bf16 xc)
  constexpr size_t S_XDBL = (size_t)NTOK*64*4;        // 0.5 MB
  constexpr size_t S_YBF  = (size_t)NTOK*DIi*2;       // 4 MB
  constexpr size_t S_INW  = (size_t)NLl*2048*512*2;   // 6 MB
  constexpr size_t S_OUTW = (size_t)NLl*512*1024*2;   // 3 MB
  constexpr size_t S_XPW  = (size_t)NLl*64*DIi*2;     // 0.4 MB (bf16 xproj_w)
  constexpr size_t S_E    = (size_t)Bb*DIi*NCH*16*4;  // 8 MB
  constexpr size_t S_TOTAL = S_X+S_XN+S_XZ+S_XC+S_XCB+S_XDBL+S_YBF
                             +S_INW+S_OUTW+S_XPW+3*S_E;

  // Safety: never scribble past the provided workspace.
  if (ws_size < S_TOTAL) return;

  size_t off = 0;
  float* x            = (float*)(ws + off);          off += S_X;
  unsigned short* xn  = (unsigned short*)(ws + off); off += S_XN;
  float* xz           = (float*)(ws + off);          off += S_XZ;
  float* xc           = (float*)(ws + off);          off += S_XC;
  unsigned short* xcbf= (unsigned short*)(ws + off); off += S_XCB;
  float* xdbl         = (float*)(ws + off);          off += S_XDBL;
  unsigned short* ybf = (unsigned short*)(ws + off); off += S_YBF;
  unsigned short* inw_bf  = (unsigned short*)(ws + off); off += S_INW;
  unsigned short* outw_bf = (unsigned short*)(ws + off); off += S_OUTW;
  unsigned short* xpw_bf  = (unsigned short*)(ws + off); off += S_XPW;
  float* Ebuf         = (float*)(ws + off);          off += S_E;
  float* Pbuf         = (float*)(ws + off);          off += S_E;
  float* H0buf        = (float*)(ws + off);          off += S_E;

  const int n_inw  = NLl*2048*512;
  const int n_outw = NLl*512*1024;
  const int n_xpw  = NLl*64*DIi;
  cast3_k<<<(n_inw+n_outw+n_xpw+255)/256, 256, 0, stream>>>(
      in_w, inw_bf, n_inw, out_w, outw_bf, n_outw, xproj_w, xpw_bf, n_xpw);

  embed_k<<<NTOK, 128, 0, stream>>>(states, actions, rtg, ctg, ts,
      W_s, b_s, W_a, b_a, W_r, b_r, W_c, b_c, E_t, x);

  for (int i=0;i<NLl;++i){
    ln_k<<<NTOK/4, 256, 0, stream>>>(x, ln_g + i*DMf, ln_b + i*DMf, xn);
    gemm_bt_k<0><<<dim3(NTOK/128, 2048/128), 256, 0, stream>>>(
        xn, inw_bf + (size_t)i*2048*512, xz, NTOK, 2048, 512);
    conv_k<<<(NTOK*DIi)/256, 256, 0, stream>>>(xz, conv_w + (size_t)i*DIi*4,
        conv_b + (size_t)i*DIi, xc, xcbf);
    xproj_mfma_k<<<NTOK/64, 256, 0, stream>>>(xcbf, xpw_bf + (size_t)i*64*DIi, xdbl);
    scan1_k<<<Bb*NCH*4, 256, 0, stream>>>(xc, xdbl,
        dtproj_w + (size_t)i*DIi*32, dtproj_b + (size_t)i*DIi,
        A_log + (size_t)i*DIi*16, Ebuf, Pbuf);
    scanmid_k<<<(Bb*DIi*16)/256, 256, 0, stream>>>(Ebuf, Pbuf, H0buf);
    scan2_k<<<Bb*NCH*4, 256, 0, stream>>>(xc, xdbl,
        dtproj_w + (size_t)i*DIi*32, dtproj_b + (size_t)i*DIi,
        A_log + (size_t)i*DIi*16, D_ssm + (size_t)i*DIi, xz, H0buf, ybf);
    gemm_bt64_k<<<dim3(NTOK/64, 512/64), 256, 0, stream>>>(
        ybf, outw_bf + (size_t)i*512*1024, x, NTOK, 512, 1024);
  }

  head_k<<<NTOK/4, 256, 0, stream>>>(x, fn_g, fn_b, W_ps, b_ps, W_pa, b_pa,
      (float*)d_out);
}

// Round 11
// 361.779 us; speedup vs baseline: 1.1822x; 1.1822x over previous
//
#include <hip/hip_runtime.h>
#include <cstdint>
#include <cstddef>

#define DMf 512
#define DM4 128
#define DIi 1024
#define DSs 16
#define DTRr 32
#define NLl 3
#define SDd 17
#define ADd 7
#define Bb 2
#define Ll 1024
#define NTOK (Bb*Ll)
#define CL 16
#define NCH 64

typedef __bf16 bf16x8 __attribute__((ext_vector_type(8)));
typedef float f32x4 __attribute__((ext_vector_type(4)));

__device__ inline unsigned short f2bf(float f){
  unsigned int u = __float_as_uint(f);
  unsigned int r = (u + 0x7FFFu + ((u>>16)&1u)) >> 16;
  return (unsigned short)r;
}
__device__ inline float silu_f(float v){ return v / (1.0f + __expf(-v)); }

// ---------------- cast fp32 -> bf16 (3 arrays in one launch) ----------------
__global__ __launch_bounds__(256) void cast3_k(
    const float* __restrict__ a, unsigned short* __restrict__ da, int na,
    const float* __restrict__ b, unsigned short* __restrict__ db, int nb,
    const float* __restrict__ c, unsigned short* __restrict__ dc, int nc){
  int i = blockIdx.x*256 + threadIdx.x;
  if (i < na) { da[i] = f2bf(a[i]); return; }
  int j = i - na;
  if (j < nb) { db[j] = f2bf(b[j]); return; }
  int k = j - nb;
  if (k < nc) dc[k] = f2bf(c[k]);
}

// ---------------- embedding ----------------
__global__ __launch_bounds__(128) void embed_k(
    const float* __restrict__ st, const float* __restrict__ ac,
    const float* __restrict__ rtg, const float* __restrict__ ctg,
    const int* __restrict__ ts,
    const float* __restrict__ Ws, const float* __restrict__ bs,
    const float* __restrict__ Wa, const float* __restrict__ ba,
    const float* __restrict__ Wr, const float* __restrict__ br,
    const float* __restrict__ Wc, const float* __restrict__ bc,
    const float* __restrict__ Et, float* __restrict__ x)
{
  int tok = blockIdx.x; int j = threadIdx.x;
  int l = tok & (Ll-1);
  int t = ts[tok];
  float te = Et[(size_t)t*DM4 + j];
  float re = rtg[tok]*Wr[j] + br[j] + te;
  float ce = ctg[tok]*Wc[j] + bc[j] + te;
  float se = bs[j] + te;
  #pragma unroll
  for (int k=0;k<SDd;++k) se += st[(size_t)tok*SDd+k]*Ws[j*SDd+k];
  float ae = 0.0f;
  if (l > 0) {
    int tp = ts[tok-1];
    ae = ba[j] + Et[(size_t)tp*DM4 + j];
    #pragma unroll
    for (int k=0;k<ADd;++k) ae += ac[(size_t)(tok-1)*ADd+k]*Wa[j*ADd+k];
  }
  float* xt = x + (size_t)tok*DMf;
  xt[0*DM4+j]=re; xt[1*DM4+j]=ce; xt[2*DM4+j]=se; xt[3*DM4+j]=ae;
}

// ---------------- layernorm -> bf16 (wave per token) ----------------
__global__ __launch_bounds__(256) void ln_k(const float* __restrict__ x,
    const float* __restrict__ g, const float* __restrict__ bta,
    unsigned short* __restrict__ xn)
{
  int wave = threadIdx.x >> 6, lane = threadIdx.x & 63;
  int tok = blockIdx.x*4 + wave;
  const float* xr = x + (size_t)tok*DMf;
  float v[8];
  float4 a = *(const float4*)&xr[lane*8];
  float4 b = *(const float4*)&xr[lane*8+4];
  v[0]=a.x; v[1]=a.y; v[2]=a.z; v[3]=a.w; v[4]=b.x; v[5]=b.y; v[6]=b.z; v[7]=b.w;
  float s = 0.f;
  #pragma unroll
  for (int j=0;j<8;++j) s += v[j];
  #pragma unroll
  for (int m=32;m>=1;m>>=1) s += __shfl_xor(s, m, 64);
  float mu = s * (1.0f/DMf);
  float vs = 0.f;
  #pragma unroll
  for (int j=0;j<8;++j){ float d = v[j]-mu; vs += d*d; }
  #pragma unroll
  for (int m=32;m>=1;m>>=1) vs += __shfl_xor(vs, m, 64);
  float rstd = rsqrtf(vs*(1.0f/DMf) + 1e-5f);
  unsigned int o[8];
  #pragma unroll
  for (int j=0;j<8;++j){
    int c = lane*8+j;
    o[j] = f2bf((v[j]-mu)*rstd*g[c] + bta[c]);
  }
  uint4 w;
  w.x = o[0] | (o[1]<<16); w.y = o[2] | (o[3]<<16);
  w.z = o[4] | (o[5]<<16); w.w = o[6] | (o[7]<<16);
  *(uint4*)&xn[(size_t)tok*DMf + lane*8] = w;
}

// ---------------- bf16 MFMA GEMM, C[M,N] = A[M,K] @ B[N,K]^T ----------------
// 128x128 tile, BK=32, 4 waves (2x2 of 64x64), global_load_lds width 16.
// Single-buffer + __syncthreads (r8/r10 A/B: explicit 2-phase pipeline neutral).
template<int ACCUM>
__global__ __launch_bounds__(256) void gemm_bt_k(const unsigned short* __restrict__ A,
    const unsigned short* __restrict__ Bm, float* __restrict__ C, int M, int N, int K)
{
  __shared__ unsigned short As[128*32];
  __shared__ unsigned short Bs[128*32];
  int tid = threadIdx.x;
  int bm = blockIdx.x, bn = blockIdx.y;
  size_t row0 = (size_t)bm*128, col0 = (size_t)bn*128;
  int wave = tid>>6, lane = tid&63;
  int wr = wave>>1, wc = wave&1;
  f32x4 acc[4][4];
  f32x4 z4 = {0.f,0.f,0.f,0.f};
  #pragma unroll
  for (int m=0;m<4;++m)
    #pragma unroll
    for (int n=0;n<4;++n) acc[m][n] = z4;
  int lrow = lane&15, lko = (lane>>4)*8;
  for (int k0=0; k0<K; k0+=32){
    #pragma unroll
    for (int r=0;r<2;++r){
      int flat = r*256 + tid;
      int arow = flat>>2, ak = (flat&3)*8;
      const unsigned short* ga = A + (row0+arow)*K + k0 + ak;
      const unsigned short* gb = Bm + (col0+arow)*K + k0 + ak;
      __builtin_amdgcn_global_load_lds((const __attribute__((address_space(1))) void*)ga,
          (__attribute__((address_space(3))) void*)(&As[flat*8]), 16, 0, 0);
      __builtin_amdgcn_global_load_lds((const __attribute__((address_space(1))) void*)gb,
          (__attribute__((address_space(3))) void*)(&Bs[flat*8]), 16, 0, 0);
    }
    __syncthreads();
    bf16x8 af[4], bfv[4];
    #pragma unroll
    for (int m=0;m<4;++m) af[m] = *(const bf16x8*)&As[(wr*64+m*16+lrow)*32 + lko];
    #pragma unroll
    for (int n=0;n<4;++n) bfv[n] = *(const bf16x8*)&Bs[(wc*64+n*16+lrow)*32 + lko];
    #pragma unroll
    for (int m=0;m<4;++m)
      #pragma unroll
      for (int n=0;n<4;++n)
        acc[m][n] = __builtin_amdgcn_mfma_f32_16x16x32_bf16(af[m], bfv[n], acc[m][n], 0, 0, 0);
    __syncthreads();
  }
  int lcol = lane&15, lr4 = (lane>>4)*4;
  #pragma unroll
  for (int m=0;m<4;++m)
    #pragma unroll
    for (int n=0;n<4;++n){
      size_t row = row0 + wr*64 + m*16 + lr4;
      size_t col = col0 + wc*64 + n*16 + lcol;
      #pragma unroll
      for (int j=0;j<4;++j){
        float vv = acc[m][n][j];
        float* p = &C[(row+j)*N + col];
        if (ACCUM) *p += vv; else *p = vv;
      }
    }
}

// ------- 64x64-tile bf16 MFMA GEMM (accumulating): C[M,N] += A[M,K] @ B[N,K]^T -------
__global__ __launch_bounds__(256) void gemm_bt64_k(const unsigned short* __restrict__ A,
    const unsigned short* __restrict__ Bm, float* __restrict__ C, int M, int N, int K)
{
  __shared__ unsigned short As[64*32];
  __shared__ unsigned short Bs[64*32];
  int tid = threadIdx.x;
  size_t row0 = (size_t)blockIdx.x*64, col0 = (size_t)blockIdx.y*64;
  int wave = tid>>6, lane = tid&63;
  int wr = wave>>1, wc = wave&1;
  f32x4 acc[2][2];
  f32x4 z4 = {0.f,0.f,0.f,0.f};
  acc[0][0]=z4; acc[0][1]=z4; acc[1][0]=z4; acc[1][1]=z4;
  int lrow = lane&15, lko = (lane>>4)*8;
  int srow = tid>>2, sk = (tid&3)*8;
  for (int k0=0; k0<K; k0+=32){
    const unsigned short* ga = A + (row0+srow)*K + k0 + sk;
    const unsigned short* gb = Bm + (col0+srow)*K + k0 + sk;
    __builtin_amdgcn_global_load_lds((const __attribute__((address_space(1))) void*)ga,
        (__attribute__((address_space(3))) void*)(&As[tid*8]), 16, 0, 0);
    __builtin_amdgcn_global_load_lds((const __attribute__((address_space(1))) void*)gb,
        (__attribute__((address_space(3))) void*)(&Bs[tid*8]), 16, 0, 0);
    __syncthreads();
    bf16x8 af[2], bfv[2];
    #pragma unroll
    for (int m=0;m<2;++m) af[m] = *(const bf16x8*)&As[(wr*32+m*16+lrow)*32 + lko];
    #pragma unroll
    for (int n=0;n<2;++n) bfv[n] = *(const bf16x8*)&Bs[(wc*32+n*16+lrow)*32 + lko];
    #pragma unroll
    for (int m=0;m<2;++m)
      #pragma unroll
      for (int n=0;n<2;++n)
        acc[m][n] = __builtin_amdgcn_mfma_f32_16x16x32_bf16(af[m], bfv[n], acc[m][n], 0, 0, 0);
    __syncthreads();
  }
  int lcol = lane&15, lr4 = (lane>>4)*4;
  #pragma unroll
  for (int m=0;m<2;++m)
    #pragma unroll
    for (int n=0;n<2;++n){
      size_t row = row0 + wr*32 + m*16 + lr4;
      size_t col = col0 + wc*32 + n*16 + lcol;
      #pragma unroll
      for (int j=0;j<4;++j)
        C[(row+j)*N + col] += acc[m][n][j];
    }
}

// ---------------- causal conv (width 4) + silu; fp32 + bf16 outputs ----------------
__global__ __launch_bounds__(256) void conv_k(const float* __restrict__ xz,
    const float* __restrict__ cw, const float* __restrict__ cb,
    float* __restrict__ xc, unsigned short* __restrict__ xcbf)
{
  int idx = blockIdx.x*256 + threadIdx.x;     // tok*DI + d
  int d = idx & (DIi-1); int tok = idx >> 10; int l = tok & (Ll-1);
  float acc = cb[d];
  #pragma unroll
  for (int k=0;k<4;++k){
    int ll = l + k - 3;
    if (ll >= 0) acc += xz[(size_t)(tok + k - 3)*(2*DIi) + d] * cw[d*4+k];
  }
  float v = silu_f(acc);
  xc[idx] = v;
  xcbf[idx] = f2bf(v);
}

// ---------------- xproj via MFMA: xdbl[2048,64] = xcbf @ xw^T, 64x64 tiles --------
__global__ __launch_bounds__(256) void xproj_mfma_k(const unsigned short* __restrict__ A,
    const unsigned short* __restrict__ Bw, float* __restrict__ xdbl)
{
  __shared__ unsigned short As[64*32];
  __shared__ unsigned short Bs[64*32];
  int tid = threadIdx.x;
  size_t row0 = (size_t)blockIdx.x*64;
  int wave = tid>>6, lane = tid&63;
  int wr = wave>>1, wc = wave&1;
  f32x4 acc[2][2];
  f32x4 z4 = {0.f,0.f,0.f,0.f};
  acc[0][0]=z4; acc[0][1]=z4; acc[1][0]=z4; acc[1][1]=z4;
  int lrow = lane&15, lko = (lane>>4)*8;
  int srow = tid>>2, sk = (tid&3)*8;
  for (int k0=0; k0<DIi; k0+=32){
    const unsigned short* ga = A + (row0+srow)*DIi + k0 + sk;
    const unsigned short* gb = Bw + (size_t)srow*DIi + k0 + sk;
    __builtin_amdgcn_global_load_lds((const __attribute__((address_space(1))) void*)ga,
        (__attribute__((address_space(3))) void*)(&As[tid*8]), 16, 0, 0);
    __builtin_amdgcn_global_load_lds((const __attribute__((address_space(1))) void*)gb,
        (__attribute__((address_space(3))) void*)(&Bs[tid*8]), 16, 0, 0);
    __syncthreads();
    bf16x8 af[2], bfv[2];
    #pragma unroll
    for (int m=0;m<2;++m) af[m] = *(const bf16x8*)&As[(wr*32+m*16+lrow)*32 + lko];
    #pragma unroll
    for (int n=0;n<2;++n) bfv[n] = *(const bf16x8*)&Bs[(wc*32+n*16+lrow)*32 + lko];
    #pragma unroll
    for (int m=0;m<2;++m)
      #pragma unroll
      for (int n=0;n<2;++n)
        acc[m][n] = __builtin_amdgcn_mfma_f32_16x16x32_bf16(af[m], bfv[n], acc[m][n], 0, 0, 0);
    __syncthreads();
  }
  int lcol = lane&15, lr4 = (lane>>4)*4;
  #pragma unroll
  for (int m=0;m<2;++m)
    #pragma unroll
    for (int n=0;n<2;++n){
      size_t row = row0 + wr*32 + m*16 + lr4;
      int col = wc*32 + n*16 + lcol;
      #pragma unroll
      for (int j=0;j<4;++j)
        xdbl[(row+j)*64 + col] = acc[m][n][j];
    }
}

// ---------------- dtproj + softplus (parallel: 8 toks x 256 outs per block) --------
// Separate kernel (r10 lesson: folding this into the scans cost ~+40us —
// doubled compute, +40 VGPR on latency-bound scans).
__global__ __launch_bounds__(256) void dtproj_k(const float* __restrict__ xdbl,
    const float* __restrict__ dw, const float* __restrict__ db, float* __restrict__ dt)
{
  int bid = blockIdx.x;
  int tok0 = (bid >> 2) * 8;
  int o = (bid & 3)*256 + threadIdx.x;
  __shared__ float lows[8][32];
  {
    int tt = threadIdx.x >> 5, kk = threadIdx.x & 31;
    lows[tt][kk] = xdbl[(size_t)(tok0+tt)*64 + kk];
  }
  __syncthreads();
  float w[32];
  #pragma unroll
  for (int q=0;q<8;++q)
    *(float4*)&w[q*4] = *(const float4*)&dw[(size_t)o*32 + q*4];
  float bias = db[o];
  #pragma unroll
  for (int t=0;t<8;++t){
    float acc = bias;
    #pragma unroll
    for (int k=0;k<32;++k) acc += w[k]*lows[t][k];
    float dv = (acc > 15.0f) ? acc : log1pf(__expf(acc));
    dt[(size_t)(tok0+t)*DIi + o] = dv;
  }
}

// ---------------- scan pass 1: per-chunk E (h_end from 0) and P (prod dA) ----------------
__global__ __launch_bounds__(256) void scan1_k(const float* __restrict__ dt,
    const float* __restrict__ xc, const float* __restrict__ xdbl,
    const float* __restrict__ Alog, float* __restrict__ Ebuf, float* __restrict__ Pbuf)
{
  int bid = blockIdx.x;
  int dblk = bid & 3; int tmp = bid >> 2; int c = tmp & (NCH-1); int b = tmp >> 6;
  int d = dblk*256 + threadIdx.x;
  float A[16], h[16], P[16];
  #pragma unroll
  for (int s=0;s<16;++s){ A[s] = -__expf(Alog[d*16+s]); h[s]=0.f; P[s]=1.f; }
  int l0 = c*CL;
  for (int l=l0; l<l0+CL; ++l){
    size_t tok = (size_t)b*Ll + l;
    float dtv = dt[tok*DIi + d];
    float u   = xc[tok*DIi + d];
    float dtu = dtv*u;
    const float* bcv = &xdbl[tok*64 + 32];
    #pragma unroll
    for (int s=0;s<16;++s){
      float dA = __expf(dtv*A[s]);
      h[s] = h[s]*dA + dtu*bcv[s];
      P[s] *= dA;
    }
  }
  size_t base = (((size_t)b*DIi + d)*NCH + c)*16;
  #pragma unroll
  for (int s=0;s<16;++s){ Ebuf[base+s]=h[s]; Pbuf[base+s]=P[s]; }
}

// ---------------- combine chunk states ----------------
__global__ __launch_bounds__(256) void scanmid_k(const float* __restrict__ E,
    const float* __restrict__ P, float* __restrict__ H0)
{
  int gid = blockIdx.x*256 + threadIdx.x;   // (b*DI+d)*16 + s
  int s = gid & 15; size_t bd = (size_t)(gid >> 4);
  float H = 0.f;
  for (int c=0;c<NCH;++c){
    size_t idx = (bd*NCH + c)*16 + s;
    H0[idx] = H;
    H = P[idx]*H + E[idx];
  }
}

// ---------------- scan pass 2: full y, gated, -> bf16 ----------------
__global__ __launch_bounds__(256) void scan2_k(const float* __restrict__ dt,
    const float* __restrict__ xc, const float* __restrict__ xdbl,
    const float* __restrict__ Alog, const float* __restrict__ Dv,
    const float* __restrict__ xz, const float* __restrict__ H0,
    unsigned short* __restrict__ ybf)
{
  int bid = blockIdx.x;
  int dblk = bid & 3; int tmp = bid >> 2; int c = tmp & (NCH-1); int b = tmp >> 6;
  int d = dblk*256 + threadIdx.x;
  size_t base = (((size_t)b*DIi + d)*NCH + c)*16;
  float A[16], h[16];
  #pragma unroll
  for (int s=0;s<16;++s){ A[s] = -__expf(Alog[d*16+s]); h[s] = H0[base+s]; }
  float Dd = Dv[d];
  int l0 = c*CL;
  for (int l=l0; l<l0+CL; ++l){
    size_t tok = (size_t)b*Ll + l;
    float dtv = dt[tok*DIi + d];
    float u   = xc[tok*DIi + d];
    float dtu = dtv*u;
    const float* bcv = &xdbl[tok*64 + 32];
    float y = 0.f;
    #pragma unroll
    for (int s=0;s<16;++s){
      float dA = __expf(dtv*A[s]);
      h[s] = h[s]*dA + dtu*bcv[s];
      y += h[s]*bcv[16+s];
    }
    float zv = xz[tok*(2*DIi) + DIi + d];
    ybf[tok*DIi + d] = f2bf((y + Dd*u) * silu_f(zv));
  }
}

// ---------------- final LN + prediction heads ----------------
__global__ __launch_bounds__(256) void head_k(const float* __restrict__ x,
    const float* __restrict__ g, const float* __restrict__ bta,
    const float* __restrict__ Wps, const float* __restrict__ bps,
    const float* __restrict__ Wpa, const float* __restrict__ bpa,
    float* __restrict__ out)
{
  __shared__ float lds[4][256];
  int wave = threadIdx.x >> 6, lane = threadIdx.x & 63;
  int tok = blockIdx.x*4 + wave;
  const float* xr = x + (size_t)tok*DMf;
  float v[8];
  float4 a = *(const float4*)&xr[lane*8];
  float4 b = *(const float4*)&xr[lane*8+4];
  v[0]=a.x; v[1]=a.y; v[2]=a.z; v[3]=a.w; v[4]=b.x; v[5]=b.y; v[6]=b.z; v[7]=b.w;
  float s = 0.f;
  #pragma unroll
  for (int j=0;j<8;++j) s += v[j];
  #pragma unroll
  for (int m=32;m>=1;m>>=1) s += __shfl_xor(s, m, 64);
  float mu = s * (1.0f/DMf);
  float vs = 0.f;
  #pragma unroll
  for (int j=0;j<8;++j){ float d = v[j]-mu; vs += d*d; }
  #pragma unroll
  for (int m=32;m>=1;m>>=1) vs += __shfl_xor(vs, m, 64);
  float rstd = rsqrtf(vs*(1.0f/DMf) + 1e-5f);
  if (lane >= 32){
    #pragma unroll
    for (int j=0;j<8;++j){
      int cdx = lane*8+j;
      lds[wave][cdx-256] = (v[j]-mu)*rstd*g[cdx] + bta[cdx];
    }
  }
  __syncthreads();
  if (lane < SDd){
    float acc = bps[lane];
    const float* w = &Wps[lane*DM4];
    #pragma unroll 8
    for (int k=0;k<DM4;++k) acc += lds[wave][128+k]*w[k];   // slot 3 (ae)
    out[(size_t)tok*SDd + lane] = acc;
  } else if (lane < SDd+ADd){
    int o = lane - SDd;
    float acc = bpa[o];
    const float* w = &Wpa[o*DM4];
    #pragma unroll 8
    for (int k=0;k<DM4;++k) acc += lds[wave][k]*w[k];       // slot 2 (se)
    out[(size_t)NTOK*SDd + (size_t)tok*ADd + o] = acc;
  }
}

extern "C" void kernel_launch(void* const* d_in, const int* in_sizes, int n_in,
                              void* d_out, int out_size, void* d_ws, size_t ws_size,
                              hipStream_t stream)
{
  (void)in_sizes; (void)n_in; (void)out_size;
  const float* states   = (const float*)d_in[0];
  const float* actions  = (const float*)d_in[1];
  const float* rtg      = (const float*)d_in[2];
  const float* ctg      = (const float*)d_in[3];
  const int*   ts       = (const int*)d_in[4];
  const float* W_s      = (const float*)d_in[5];
  const float* b_s      = (const float*)d_in[6];
  const float* W_a      = (const float*)d_in[7];
  const float* b_a      = (const float*)d_in[8];
  const float* W_r      = (const float*)d_in[9];
  const float* b_r      = (const float*)d_in[10];
  const float* W_c      = (const float*)d_in[11];
  const float* b_c      = (const float*)d_in[12];
  const float* E_t      = (const float*)d_in[13];
  const float* ln_g     = (const float*)d_in[14];
  const float* ln_b     = (const float*)d_in[15];
  const float* in_w     = (const float*)d_in[16];
  const float* conv_w   = (const float*)d_in[17];
  const float* conv_b   = (const float*)d_in[18];
  const float* xproj_w  = (const float*)d_in[19];
  const float* dtproj_w = (const float*)d_in[20];
  const float* dtproj_b = (const float*)d_in[21];
  const float* A_log    = (const float*)d_in[22];
  const float* D_ssm    = (const float*)d_in[23];
  const float* out_w    = (const float*)d_in[24];
  const float* fn_g     = (const float*)d_in[25];
  const float* fn_b     = (const float*)d_in[26];
  const float* W_ps     = (const float*)d_in[27];
  const float* b_ps     = (const float*)d_in[28];
  const float* W_pa     = (const float*)d_in[29];
  const float* b_pa     = (const float*)d_in[30];

  char* ws = (char*)d_ws;
  constexpr size_t S_X    = (size_t)NTOK*DMf*4;       // 4 MB
  constexpr size_t S_XN   = (size_t)NTOK*DMf*2;       // 2 MB
  constexpr size_t S_XZ   = (size_t)NTOK*2*DIi*4;     // 16 MB
  constexpr size_t S_XC   = (size_t)NTOK*DIi*4;       // 8 MB
  constexpr size_t S_XCB  = (size_t)NTOK*DIi*2;       // 4 MB (bf16 xc)
  constexpr size_t S_XDBL = (size_t)NTOK*64*4;        // 0.5 MB
  constexpr size_t S_DT   = (size_t)NTOK*DIi*4;       // 8 MB
  constexpr size_t S_YBF  = (size_t)NTOK*DIi*2;       // 4 MB
  constexpr size_t S_INW  = (size_t)NLl*2048*512*2;   // 6 MB
  constexpr size_t S_OUTW = (size_t)NLl*512*1024*2;   // 3 MB
  constexpr size_t S_XPW  = (size_t)NLl*64*DIi*2;     // 0.4 MB (bf16 xproj_w)
  constexpr size_t S_E    = (size_t)Bb*DIi*NCH*16*4;  // 8 MB
  constexpr size_t S_TOTAL = S_X+S_XN+S_XZ+S_XC+S_XCB+S_XDBL+S_DT+S_YBF
                             +S_INW+S_OUTW+S_XPW+3*S_E;

  // Safety: never scribble past the provided workspace.
  if (ws_size < S_TOTAL) return;

  size_t off = 0;
  float* x            = (float*)(ws + off);          off += S_X;
  unsigned short* xn  = (unsigned short*)(ws + off); off += S_XN;
  float* xz           = (float*)(ws + off);          off += S_XZ;
  float* xc           = (float*)(ws + off);          off += S_XC;
  unsigned short* xcbf= (unsigned short*)(ws + off); off += S_XCB;
  float* xdbl         = (float*)(ws + off);          off += S_XDBL;
  float* dt           = (float*)(ws + off);          off += S_DT;
  unsigned short* ybf = (unsigned short*)(ws + off); off += S_YBF;
  unsigned short* inw_bf  = (unsigned short*)(ws + off); off += S_INW;
  unsigned short* outw_bf = (unsigned short*)(ws + off); off += S_OUTW;
  unsigned short* xpw_bf  = (unsigned short*)(ws + off); off += S_XPW;
  float* Ebuf         = (float*)(ws + off);          off += S_E;
  float* Pbuf         = (float*)(ws + off);          off += S_E;
  float* H0buf        = (float*)(ws + off);          off += S_E;

  const int n_inw  = NLl*2048*512;
  const int n_outw = NLl*512*1024;
  const int n_xpw  = NLl*64*DIi;
  cast3_k<<<(n_inw+n_outw+n_xpw+255)/256, 256, 0, stream>>>(
      in_w, inw_bf, n_inw, out_w, outw_bf, n_outw, xproj_w, xpw_bf, n_xpw);

  embed_k<<<NTOK, 128, 0, stream>>>(states, actions, rtg, ctg, ts,
      W_s, b_s, W_a, b_a, W_r, b_r, W_c, b_c, E_t, x);

  for (int i=0;i<NLl;++i){
    ln_k<<<NTOK/4, 256, 0, stream>>>(x, ln_g + i*DMf, ln_b + i*DMf, xn);
    gemm_bt_k<0><<<dim3(NTOK/128, 2048/128), 256, 0, stream>>>(
        xn, inw_bf + (size_t)i*2048*512, xz, NTOK, 2048, 512);
    conv_k<<<(NTOK*DIi)/256, 256, 0, stream>>>(xz, conv_w + (size_t)i*DIi*4,
        conv_b + (size_t)i*DIi, xc, xcbf);
    xproj_mfma_k<<<NTOK/64, 256, 0, stream>>>(xcbf, xpw_bf + (size_t)i*64*DIi, xdbl);
    dtproj_k<<<(NTOK/8)*4, 256, 0, stream>>>(xdbl, dtproj_w + (size_t)i*DIi*32,
        dtproj_b + (size_t)i*DIi, dt);
    scan1_k<<<Bb*NCH*4, 256, 0, stream>>>(dt, xc, xdbl,
        A_log + (size_t)i*DIi*16, Ebuf, Pbuf);
    scanmid_k<<<(Bb*DIi*16)/256, 256, 0, stream>>>(Ebuf, Pbuf, H0buf);
    scan2_k<<<Bb*NCH*4, 256, 0, stream>>>(dt, xc, xdbl,
        A_log + (size_t)i*DIi*16, D_ssm + (size_t)i*DIi, xz, H0buf, ybf);
    gemm_bt64_k<<<dim3(NTOK/64, 512/64), 256, 0, stream>>>(
        ybf, outw_bf + (size_t)i*512*1024, x, NTOK, 512, 1024);
  }

  head_k<<<NTOK/4, 256, 0, stream>>>(x, fn_g, fn_b, W_ps, b_ps, W_pa, b_pa,
      (float*)d_out);
}

// Round 12
// 354.925 us; speedup vs baseline: 1.2050x; 1.0193x over previous
//
#include <hip/hip_runtime.h>
#include <cstdint>
#include <cstddef>

#define DMf 512
#define DM4 128
#define DIi 1024
#define DSs 16
#define DTRr 32
#define NLl 3
#define SDd 17
#define ADd 7
#define Bb 2
#define Ll 1024
#define NTOK (Bb*Ll)
#define CL 16
#define NCH 64

typedef __bf16 bf16x8 __attribute__((ext_vector_type(8)));
typedef float f32x4 __attribute__((ext_vector_type(4)));

__device__ inline unsigned short f2bf(float f){
  unsigned int u = __float_as_uint(f);
  unsigned int r = (u + 0x7FFFu + ((u>>16)&1u)) >> 16;
  return (unsigned short)r;
}
__device__ inline float silu_f(float v){ return v / (1.0f + __expf(-v)); }

// ---------------- cast fp32 -> bf16 (3 arrays in one launch) ----------------
__global__ __launch_bounds__(256) void cast3_k(
    const float* __restrict__ a, unsigned short* __restrict__ da, int na,
    const float* __restrict__ b, unsigned short* __restrict__ db, int nb,
    const float* __restrict__ c, unsigned short* __restrict__ dc, int nc){
  int i = blockIdx.x*256 + threadIdx.x;
  if (i < na) { da[i] = f2bf(a[i]); return; }
  int j = i - na;
  if (j < nb) { db[j] = f2bf(b[j]); return; }
  int k = j - nb;
  if (k < nc) dc[k] = f2bf(c[k]);
}

// ---------------- embedding ----------------
__global__ __launch_bounds__(128) void embed_k(
    const float* __restrict__ st, const float* __restrict__ ac,
    const float* __restrict__ rtg, const float* __restrict__ ctg,
    const int* __restrict__ ts,
    const float* __restrict__ Ws, const float* __restrict__ bs,
    const float* __restrict__ Wa, const float* __restrict__ ba,
    const float* __restrict__ Wr, const float* __restrict__ br,
    const float* __restrict__ Wc, const float* __restrict__ bc,
    const float* __restrict__ Et, float* __restrict__ x)
{
  int tok = blockIdx.x; int j = threadIdx.x;
  int l = tok & (Ll-1);
  int t = ts[tok];
  float te = Et[(size_t)t*DM4 + j];
  float re = rtg[tok]*Wr[j] + br[j] + te;
  float ce = ctg[tok]*Wc[j] + bc[j] + te;
  float se = bs[j] + te;
  #pragma unroll
  for (int k=0;k<SDd;++k) se += st[(size_t)tok*SDd+k]*Ws[j*SDd+k];
  float ae = 0.0f;
  if (l > 0) {
    int tp = ts[tok-1];
    ae = ba[j] + Et[(size_t)tp*DM4 + j];
    #pragma unroll
    for (int k=0;k<ADd;++k) ae += ac[(size_t)(tok-1)*ADd+k]*Wa[j*ADd+k];
  }
  float* xt = x + (size_t)tok*DMf;
  xt[0*DM4+j]=re; xt[1*DM4+j]=ce; xt[2*DM4+j]=se; xt[3*DM4+j]=ae;
}

// ---------------- layernorm -> bf16 (wave per token) ----------------
__global__ __launch_bounds__(256) void ln_k(const float* __restrict__ x,
    const float* __restrict__ g, const float* __restrict__ bta,
    unsigned short* __restrict__ xn)
{
  int wave = threadIdx.x >> 6, lane = threadIdx.x & 63;
  int tok = blockIdx.x*4 + wave;
  const float* xr = x + (size_t)tok*DMf;
  float v[8];
  float4 a = *(const float4*)&xr[lane*8];
  float4 b = *(const float4*)&xr[lane*8+4];
  v[0]=a.x; v[1]=a.y; v[2]=a.z; v[3]=a.w; v[4]=b.x; v[5]=b.y; v[6]=b.z; v[7]=b.w;
  float s = 0.f;
  #pragma unroll
  for (int j=0;j<8;++j) s += v[j];
  #pragma unroll
  for (int m=32;m>=1;m>>=1) s += __shfl_xor(s, m, 64);
  float mu = s * (1.0f/DMf);
  float vs = 0.f;
  #pragma unroll
  for (int j=0;j<8;++j){ float d = v[j]-mu; vs += d*d; }
  #pragma unroll
  for (int m=32;m>=1;m>>=1) vs += __shfl_xor(vs, m, 64);
  float rstd = rsqrtf(vs*(1.0f/DMf) + 1e-5f);
  unsigned int o[8];
  #pragma unroll
  for (int j=0;j<8;++j){
    int c = lane*8+j;
    o[j] = f2bf((v[j]-mu)*rstd*g[c] + bta[c]);
  }
  uint4 w;
  w.x = o[0] | (o[1]<<16); w.y = o[2] | (o[3]<<16);
  w.z = o[4] | (o[5]<<16); w.w = o[6] | (o[7]<<16);
  *(uint4*)&xn[(size_t)tok*DMf + lane*8] = w;
}

// ---- in_proj GEMM: C[M,N] = A[M,K] @ B[N,K]^T, 128x64 tile, BK=32 ----
// r11: 128x128 tile -> grid 256 = exactly 1 block/CU -> zero co-residency,
// every barrier drain exposed. 128x64 -> 512 blocks = 2/CU (m114 overlap).
__global__ __launch_bounds__(256) void gemm_in_k(const unsigned short* __restrict__ A,
    const unsigned short* __restrict__ Bm, float* __restrict__ C, int M, int N, int K)
{
  __shared__ unsigned short As[128*32];
  __shared__ unsigned short Bs[64*32];
  int tid = threadIdx.x;
  size_t row0 = (size_t)blockIdx.x*128, col0 = (size_t)blockIdx.y*64;
  int wave = tid>>6, lane = tid&63;
  int wr = wave>>1, wc = wave&1;       // wave = 64 rows x 32 cols
  f32x4 acc[4][2];
  f32x4 z4 = {0.f,0.f,0.f,0.f};
  #pragma unroll
  for (int m=0;m<4;++m){ acc[m][0]=z4; acc[m][1]=z4; }
  int lrow = lane&15, lko = (lane>>4)*8;
  for (int k0=0; k0<K; k0+=32){
    #pragma unroll
    for (int r=0;r<2;++r){
      int flat = r*256 + tid;
      int arow = flat>>2, ak = (flat&3)*8;
      const unsigned short* ga = A + (row0+arow)*K + k0 + ak;
      __builtin_amdgcn_global_load_lds((const __attribute__((address_space(1))) void*)ga,
          (__attribute__((address_space(3))) void*)(&As[flat*8]), 16, 0, 0);
    }
    {
      int brow = tid>>2, bk = (tid&3)*8;
      const unsigned short* gb = Bm + (col0+brow)*K + k0 + bk;
      __builtin_amdgcn_global_load_lds((const __attribute__((address_space(1))) void*)gb,
          (__attribute__((address_space(3))) void*)(&Bs[tid*8]), 16, 0, 0);
    }
    __syncthreads();
    bf16x8 af[4], bfv[2];
    #pragma unroll
    for (int m=0;m<4;++m) af[m] = *(const bf16x8*)&As[(wr*64+m*16+lrow)*32 + lko];
    #pragma unroll
    for (int n=0;n<2;++n) bfv[n] = *(const bf16x8*)&Bs[(wc*32+n*16+lrow)*32 + lko];
    #pragma unroll
    for (int m=0;m<4;++m)
      #pragma unroll
      for (int n=0;n<2;++n)
        acc[m][n] = __builtin_amdgcn_mfma_f32_16x16x32_bf16(af[m], bfv[n], acc[m][n], 0, 0, 0);
    __syncthreads();
  }
  int lcol = lane&15, lr4 = (lane>>4)*4;
  #pragma unroll
  for (int m=0;m<4;++m)
    #pragma unroll
    for (int n=0;n<2;++n){
      size_t row = row0 + wr*64 + m*16 + lr4;
      size_t col = col0 + wc*32 + n*16 + lcol;
      #pragma unroll
      for (int j=0;j<4;++j)
        C[(row+j)*N + col] = acc[m][n][j];
    }
}

// ------- 64x64-tile bf16 MFMA GEMM (accumulating): C[M,N] += A[M,K] @ B[N,K]^T -------
__global__ __launch_bounds__(256) void gemm_bt64_k(const unsigned short* __restrict__ A,
    const unsigned short* __restrict__ Bm, float* __restrict__ C, int M, int N, int K)
{
  __shared__ unsigned short As[64*32];
  __shared__ unsigned short Bs[64*32];
  int tid = threadIdx.x;
  size_t row0 = (size_t)blockIdx.x*64, col0 = (size_t)blockIdx.y*64;
  int wave = tid>>6, lane = tid&63;
  int wr = wave>>1, wc = wave&1;
  f32x4 acc[2][2];
  f32x4 z4 = {0.f,0.f,0.f,0.f};
  acc[0][0]=z4; acc[0][1]=z4; acc[1][0]=z4; acc[1][1]=z4;
  int lrow = lane&15, lko = (lane>>4)*8;
  int srow = tid>>2, sk = (tid&3)*8;
  for (int k0=0; k0<K; k0+=32){
    const unsigned short* ga = A + (row0+srow)*K + k0 + sk;
    const unsigned short* gb = Bm + (col0+srow)*K + k0 + sk;
    __builtin_amdgcn_global_load_lds((const __attribute__((address_space(1))) void*)ga,
        (__attribute__((address_space(3))) void*)(&As[tid*8]), 16, 0, 0);
    __builtin_amdgcn_global_load_lds((const __attribute__((address_space(1))) void*)gb,
        (__attribute__((address_space(3))) void*)(&Bs[tid*8]), 16, 0, 0);
    __syncthreads();
    bf16x8 af[2], bfv[2];
    #pragma unroll
    for (int m=0;m<2;++m) af[m] = *(const bf16x8*)&As[(wr*32+m*16+lrow)*32 + lko];
    #pragma unroll
    for (int n=0;n<2;++n) bfv[n] = *(const bf16x8*)&Bs[(wc*32+n*16+lrow)*32 + lko];
    #pragma unroll
    for (int m=0;m<2;++m)
      #pragma unroll
      for (int n=0;n<2;++n)
        acc[m][n] = __builtin_amdgcn_mfma_f32_16x16x32_bf16(af[m], bfv[n], acc[m][n], 0, 0, 0);
    __syncthreads();
  }
  int lcol = lane&15, lr4 = (lane>>4)*4;
  #pragma unroll
  for (int m=0;m<2;++m)
    #pragma unroll
    for (int n=0;n<2;++n){
      size_t row = row0 + wr*32 + m*16 + lr4;
      size_t col = col0 + wc*32 + n*16 + lcol;
      #pragma unroll
      for (int j=0;j<4;++j)
        C[(row+j)*N + col] += acc[m][n][j];
    }
}

// ---------------- causal conv (width 4) + silu; fp32 + bf16 outputs ----------------
__global__ __launch_bounds__(256) void conv_k(const float* __restrict__ xz,
    const float* __restrict__ cw, const float* __restrict__ cb,
    float* __restrict__ xc, unsigned short* __restrict__ xcbf)
{
  int idx = blockIdx.x*256 + threadIdx.x;     // tok*DI + d
  int d = idx & (DIi-1); int tok = idx >> 10; int l = tok & (Ll-1);
  float acc = cb[d];
  #pragma unroll
  for (int k=0;k<4;++k){
    int ll = l + k - 3;
    if (ll >= 0) acc += xz[(size_t)(tok + k - 3)*(2*DIi) + d] * cw[d*4+k];
  }
  float v = silu_f(acc);
  xc[idx] = v;
  xcbf[idx] = f2bf(v);
}

// ---------------- xproj via MFMA: xdbl[2048,64] = xcbf @ xw^T, 64x64 tiles --------
__global__ __launch_bounds__(256) void xproj_mfma_k(const unsigned short* __restrict__ A,
    const unsigned short* __restrict__ Bw, float* __restrict__ xdbl)
{
  __shared__ unsigned short As[64*32];
  __shared__ unsigned short Bs[64*32];
  int tid = threadIdx.x;
  size_t row0 = (size_t)blockIdx.x*64;
  int wave = tid>>6, lane = tid&63;
  int wr = wave>>1, wc = wave&1;
  f32x4 acc[2][2];
  f32x4 z4 = {0.f,0.f,0.f,0.f};
  acc[0][0]=z4; acc[0][1]=z4; acc[1][0]=z4; acc[1][1]=z4;
  int lrow = lane&15, lko = (lane>>4)*8;
  int srow = tid>>2, sk = (tid&3)*8;
  for (int k0=0; k0<DIi; k0+=32){
    const unsigned short* ga = A + (row0+srow)*DIi + k0 + sk;
    const unsigned short* gb = Bw + (size_t)srow*DIi + k0 + sk;
    __builtin_amdgcn_global_load_lds((const __attribute__((address_space(1))) void*)ga,
        (__attribute__((address_space(3))) void*)(&As[tid*8]), 16, 0, 0);
    __builtin_amdgcn_global_load_lds((const __attribute__((address_space(1))) void*)gb,
        (__attribute__((address_space(3))) void*)(&Bs[tid*8]), 16, 0, 0);
    __syncthreads();
    bf16x8 af[2], bfv[2];
    #pragma unroll
    for (int m=0;m<2;++m) af[m] = *(const bf16x8*)&As[(wr*32+m*16+lrow)*32 + lko];
    #pragma unroll
    for (int n=0;n<2;++n) bfv[n] = *(const bf16x8*)&Bs[(wc*32+n*16+lrow)*32 + lko];
    #pragma unroll
    for (int m=0;m<2;++m)
      #pragma unroll
      for (int n=0;n<2;++n)
        acc[m][n] = __builtin_amdgcn_mfma_f32_16x16x32_bf16(af[m], bfv[n], acc[m][n], 0, 0, 0);
    __syncthreads();
  }
  int lcol = lane&15, lr4 = (lane>>4)*4;
  #pragma unroll
  for (int m=0;m<2;++m)
    #pragma unroll
    for (int n=0;n<2;++n){
      size_t row = row0 + wr*32 + m*16 + lr4;
      int col = wc*32 + n*16 + lcol;
      #pragma unroll
      for (int j=0;j<4;++j)
        xdbl[(row+j)*64 + col] = acc[m][n][j];
    }
}

// ---------------- dtproj + softplus (parallel: 8 toks x 256 outs per block) --------
// Separate kernel (r10 lesson: folding this into the scans cost ~+40us).
__global__ __launch_bounds__(256) void dtproj_k(const float* __restrict__ xdbl,
    const float* __restrict__ dw, const float* __restrict__ db, float* __restrict__ dt)
{
  int bid = blockIdx.x;
  int tok0 = (bid >> 2) * 8;
  int o = (bid & 3)*256 + threadIdx.x;
  __shared__ float lows[8][32];
  {
    int tt = threadIdx.x >> 5, kk = threadIdx.x & 31;
    lows[tt][kk] = xdbl[(size_t)(tok0+tt)*64 + kk];
  }
  __syncthreads();
  float w[32];
  #pragma unroll
  for (int q=0;q<8;++q)
    *(float4*)&w[q*4] = *(const float4*)&dw[(size_t)o*32 + q*4];
  float bias = db[o];
  #pragma unroll
  for (int t=0;t<8;++t){
    float acc = bias;
    #pragma unroll
    for (int k=0;k<32;++k) acc += w[k]*lows[t][k];
    float dv = (acc > 15.0f) ? acc : log1pf(__expf(acc));
    dt[(size_t)(tok0+t)*DIi + o] = dv;
  }
}

// ---------------- scan pass 1: per-chunk E (h_end from 0) and P (prod dA) ----------------
__global__ __launch_bounds__(256) void scan1_k(const float* __restrict__ dt,
    const float* __restrict__ xc, const float* __restrict__ xdbl,
    const float* __restrict__ Alog, float* __restrict__ Ebuf, float* __restrict__ Pbuf)
{
  int bid = blockIdx.x;
  int dblk = bid & 3; int tmp = bid >> 2; int c = tmp & (NCH-1); int b = tmp >> 6;
  int d = dblk*256 + threadIdx.x;
  float A[16], h[16], P[16];
  #pragma unroll
  for (int s=0;s<16;++s){ A[s] = -__expf(Alog[d*16+s]); h[s]=0.f; P[s]=1.f; }
  int l0 = c*CL;
  for (int l=l0; l<l0+CL; ++l){
    size_t tok = (size_t)b*Ll + l;
    float dtv = dt[tok*DIi + d];
    float u   = xc[tok*DIi + d];
    float dtu = dtv*u;
    const float* bcv = &xdbl[tok*64 + 32];
    #pragma unroll
    for (int s=0;s<16;++s){
      float dA = __expf(dtv*A[s]);
      h[s] = h[s]*dA + dtu*bcv[s];
      P[s] *= dA;
    }
  }
  size_t base = (((size_t)b*DIi + d)*NCH + c)*16;
  #pragma unroll
  for (int s=0;s<16;++s){ Ebuf[base+s]=h[s]; Pbuf[base+s]=P[s]; }
}

// ---------------- combine chunk states ----------------
__global__ __launch_bounds__(256) void scanmid_k(const float* __restrict__ E,
    const float* __restrict__ P, float* __restrict__ H0)
{
  int gid = blockIdx.x*256 + threadIdx.x;   // (b*DI+d)*16 + s
  int s = gid & 15; size_t bd = (size_t)(gid >> 4);
  float H = 0.f;
  for (int c=0;c<NCH;++c){
    size_t idx = (bd*NCH + c)*16 + s;
    H0[idx] = H;
    H = P[idx]*H + E[idx];
  }
}

// ---------------- scan pass 2: full y, gated, -> bf16 ----------------
__global__ __launch_bounds__(256) void scan2_k(const float* __restrict__ dt,
    const float* __restrict__ xc, const float* __restrict__ xdbl,
    const float* __restrict__ Alog, const float* __restrict__ Dv,
    const float* __restrict__ xz, const float* __restrict__ H0,
    unsigned short* __restrict__ ybf)
{
  int bid = blockIdx.x;
  int dblk = bid & 3; int tmp = bid >> 2; int c = tmp & (NCH-1); int b = tmp >> 6;
  int d = dblk*256 + threadIdx.x;
  size_t base = (((size_t)b*DIi + d)*NCH + c)*16;
  float A[16], h[16];
  #pragma unroll
  for (int s=0;s<16;++s){ A[s] = -__expf(Alog[d*16+s]); h[s] = H0[base+s]; }
  float Dd = Dv[d];
  int l0 = c*CL;
  for (int l=l0; l<l0+CL; ++l){
    size_t tok = (size_t)b*Ll + l;
    float dtv = dt[tok*DIi + d];
    float u   = xc[tok*DIi + d];
    float dtu = dtv*u;
    const float* bcv = &xdbl[tok*64 + 32];
    float y = 0.f;
    #pragma unroll
    for (int s=0;s<16;++s){
      float dA = __expf(dtv*A[s]);
      h[s] = h[s]*dA + dtu*bcv[s];
      y += h[s]*bcv[16+s];
    }
    float zv = xz[tok*(2*DIi) + DIi + d];
    ybf[tok*DIi + d] = f2bf((y + Dd*u) * silu_f(zv));
  }
}

// ---------------- final LN + prediction heads ----------------
__global__ __launch_bounds__(256) void head_k(const float* __restrict__ x,
    const float* __restrict__ g, const float* __restrict__ bta,
    const float* __restrict__ Wps, const float* __restrict__ bps,
    const float* __restrict__ Wpa, const float* __restrict__ bpa,
    float* __restrict__ out)
{
  __shared__ float lds[4][256];
  int wave = threadIdx.x >> 6, lane = threadIdx.x & 63;
  int tok = blockIdx.x*4 + wave;
  const float* xr = x + (size_t)tok*DMf;
  float v[8];
  float4 a = *(const float4*)&xr[lane*8];
  float4 b = *(const float4*)&xr[lane*8+4];
  v[0]=a.x; v[1]=a.y; v[2]=a.z; v[3]=a.w; v[4]=b.x; v[5]=b.y; v[6]=b.z; v[7]=b.w;
  float s = 0.f;
  #pragma unroll
  for (int j=0;j<8;++j) s += v[j];
  #pragma unroll
  for (int m=32;m>=1;m>>=1) s += __shfl_xor(s, m, 64);
  float mu = s * (1.0f/DMf);
  float vs = 0.f;
  #pragma unroll
  for (int j=0;j<8;++j){ float d = v[j]-mu; vs += d*d; }
  #pragma unroll
  for (int m=32;m>=1;m>>=1) vs += __shfl_xor(vs, m, 64);
  float rstd = rsqrtf(vs*(1.0f/DMf) + 1e-5f);
  if (lane >= 32){
    #pragma unroll
    for (int j=0;j<8;++j){
      int cdx = lane*8+j;
      lds[wave][cdx-256] = (v[j]-mu)*rstd*g[cdx] + bta[cdx];
    }
  }
  __syncthreads();
  if (lane < SDd){
    float acc = bps[lane];
    const float* w = &Wps[lane*DM4];
    #pragma unroll 8
    for (int k=0;k<DM4;++k) acc += lds[wave][128+k]*w[k];   // slot 3 (ae)
    out[(size_t)tok*SDd + lane] = acc;
  } else if (lane < SDd+ADd){
    int o = lane - SDd;
    float acc = bpa[o];
    const float* w = &Wpa[o*DM4];
    #pragma unroll 8
    for (int k=0;k<DM4;++k) acc += lds[wave][k]*w[k];       // slot 2 (se)
    out[(size_t)NTOK*SDd + (size_t)tok*ADd + o] = acc;
  }
}

extern "C" void kernel_launch(void* const* d_in, const int* in_sizes, int n_in,
                              void* d_out, int out_size, void* d_ws, size_t ws_size,
                              hipStream_t stream)
{
  (void)in_sizes; (void)n_in; (void)out_size;
  const float* states   = (const float*)d_in[0];
  const float* actions  = (const float*)d_in[1];
  const float* rtg      = (const float*)d_in[2];
  const float* ctg      = (const float*)d_in[3];
  const int*   ts       = (const int*)d_in[4];
  const float* W_s      = (const float*)d_in[5];
  const float* b_s      = (const float*)d_in[6];
  const float* W_a      = (const float*)d_in[7];
  const float* b_a      = (const float*)d_in[8];
  const float* W_r      = (const float*)d_in[9];
  const float* b_r      = (const float*)d_in[10];
  const float* W_c      = (const float*)d_in[11];
  const float* b_c      = (const float*)d_in[12];
  const float* E_t      = (const float*)d_in[13];
  const float* ln_g     = (const float*)d_in[14];
  const float* ln_b     = (const float*)d_in[15];
  const float* in_w     = (const float*)d_in[16];
  const float* conv_w   = (const float*)d_in[17];
  const float* conv_b   = (const float*)d_in[18];
  const float* xproj_w  = (const float*)d_in[19];
  const float* dtproj_w = (const float*)d_in[20];
  const float* dtproj_b = (const float*)d_in[21];
  const float* A_log    = (const float*)d_in[22];
  const float* D_ssm    = (const float*)d_in[23];
  const float* out_w    = (const float*)d_in[24];
  const float* fn_g     = (const float*)d_in[25];
  const float* fn_b     = (const float*)d_in[26];
  const float* W_ps     = (const float*)d_in[27];
  const float* b_ps     = (const float*)d_in[28];
  const float* W_pa     = (const float*)d_in[29];
  const float* b_pa     = (const float*)d_in[30];

  char* ws = (char*)d_ws;
  constexpr size_t S_X    = (size_t)NTOK*DMf*4;       // 4 MB
  constexpr size_t S_XN   = (size_t)NTOK*DMf*2;       // 2 MB
  constexpr size_t S_XZ   = (size_t)NTOK*2*DIi*4;     // 16 MB
  constexpr size_t S_XC   = (size_t)NTOK*DIi*4;       // 8 MB
  constexpr size_t S_XCB  = (size_t)NTOK*DIi*2;       // 4 MB (bf16 xc)
  constexpr size_t S_XDBL = (size_t)NTOK*64*4;        // 0.5 MB
  constexpr size_t S_DT   = (size_t)NTOK*DIi*4;       // 8 MB
  constexpr size_t S_YBF  = (size_t)NTOK*DIi*2;       // 4 MB
  constexpr size_t S_INW  = (size_t)NLl*2048*512*2;   // 6 MB
  constexpr size_t S_OUTW = (size_t)NLl*512*1024*2;   // 3 MB
  constexpr size_t S_XPW  = (size_t)NLl*64*DIi*2;     // 0.4 MB (bf16 xproj_w)
  constexpr size_t S_E    = (size_t)Bb*DIi*NCH*16*4;  // 8 MB
  constexpr size_t S_TOTAL = S_X+S_XN+S_XZ+S_XC+S_XCB+S_XDBL+S_DT+S_YBF
                             +S_INW+S_OUTW+S_XPW+3*S_E;

  // Safety: never scribble past the provided workspace.
  if (ws_size < S_TOTAL) return;

  size_t off = 0;
  float* x            = (float*)(ws + off);          off += S_X;
  unsigned short* xn  = (unsigned short*)(ws + off); off += S_XN;
  float* xz           = (float*)(ws + off);          off += S_XZ;
  float* xc           = (float*)(ws + off);          off += S_XC;
  unsigned short* xcbf= (unsigned short*)(ws + off); off += S_XCB;
  float* xdbl         = (float*)(ws + off);          off += S_XDBL;
  float* dt           = (float*)(ws + off);          off += S_DT;
  unsigned short* ybf = (unsigned short*)(ws + off); off += S_YBF;
  unsigned short* inw_bf  = (unsigned short*)(ws + off); off += S_INW;
  unsigned short* outw_bf = (unsigned short*)(ws + off); off += S_OUTW;
  unsigned short* xpw_bf  = (unsigned short*)(ws + off); off += S_XPW;
  float* Ebuf         = (float*)(ws + off);          off += S_E;
  float* Pbuf         = (float*)(ws + off);          off += S_E;
  float* H0buf        = (float*)(ws + off);          off += S_E;

  const int n_inw  = NLl*2048*512;
  const int n_outw = NLl*512*1024;
  const int n_xpw  = NLl*64*DIi;
  cast3_k<<<(n_inw+n_outw+n_xpw+255)/256, 256, 0, stream>>>(
      in_w, inw_bf, n_inw, out_w, outw_bf, n_outw, xproj_w, xpw_bf, n_xpw);

  embed_k<<<NTOK, 128, 0, stream>>>(states, actions, rtg, ctg, ts,
      W_s, b_s, W_a, b_a, W_r, b_r, W_c, b_c, E_t, x);

  for (int i=0;i<NLl;++i){
    ln_k<<<NTOK/4, 256, 0, stream>>>(x, ln_g + i*DMf, ln_b + i*DMf, xn);
    gemm_in_k<<<dim3(NTOK/128, 2048/64), 256, 0, stream>>>(
        xn, inw_bf + (size_t)i*2048*512, xz, NTOK, 2048, 512);
    conv_k<<<(NTOK*DIi)/256, 256, 0, stream>>>(xz, conv_w + (size_t)i*DIi*4,
        conv_b + (size_t)i*DIi, xc, xcbf);
    xproj_mfma_k<<<NTOK/64, 256, 0, stream>>>(xcbf, xpw_bf + (size_t)i*64*DIi, xdbl);
    dtproj_k<<<(NTOK/8)*4, 256, 0, stream>>>(xdbl, dtproj_w + (size_t)i*DIi*32,
        dtproj_b + (size_t)i*DIi, dt);
    scan1_k<<<Bb*NCH*4, 256, 0, stream>>>(dt, xc, xdbl,
        A_log + (size_t)i*DIi*16, Ebuf, Pbuf);
    scanmid_k<<<(Bb*DIi*16)/256, 256, 0, stream>>>(Ebuf, Pbuf, H0buf);
    scan2_k<<<Bb*NCH*4, 256, 0, stream>>>(dt, xc, xdbl,
        A_log + (size_t)i*DIi*16, D_ssm + (size_t)i*DIi, xz, H0buf, ybf);
    gemm_bt64_k<<<dim3(NTOK/64, 512/64), 256, 0, stream>>>(
        ybf, outw_bf + (size_t)i*512*1024, x, NTOK, 512, 1024);
  }

  head_k<<<NTOK/4, 256, 0, stream>>>(x, fn_g, fn_b, W_ps, b_ps, W_pa, b_pa,
      (float*)d_out);
}